// Round 1
// baseline (2463.844 us; speedup 1.0000x reference)
//
#include <hip/hip_runtime.h>
#include <hip/hip_bf16.h>
#include <math.h>

// Problem constants
#define Bb   64
#define Nn   2048
#define Cc   512
#define Ee   32
#define E2v  64
#define Aa   8
#define INp  512
#define Hh   64
#define NM1  2047   // N-1 rows used after val[:,1:,:]

__device__ __forceinline__ float gelu_f(float x){
    return 0.5f * x * (1.0f + erff(x * 0.70710678118654752440f));
}
__device__ __forceinline__ float selu_f(float x){
    const float lam = 1.0507009873554805f, alp = 1.6732632423543772f;
    return x > 0.0f ? lam * x : lam * alp * (expf(x) - 1.0f);
}
__device__ __forceinline__ float rho_f(float x){
    return x > 0.0f ? sqrtf(x) : -sqrtf(-x);
}

// ---------------------------------------------------------------- init
__global__ __launch_bounds__(256) void k_init(float* __restrict__ outp,
                                              unsigned* __restrict__ colmax){
    int i = blockIdx.x * 256 + threadIdx.x;
    if (i < Bb * INp) { outp[i] = 0.0f; colmax[i] = 0u; }
}

// ------------------------------------------------- Q + folded Wqk/bqk
// Wqk[b][e][c] = sum_a Q[b][a*64+e] * Wk_w[a*64+e][c];  bqk likewise with Wk_b.
__global__ __launch_bounds__(256) void k_qwqk(
    const float* __restrict__ node, const float* __restrict__ Wq_w,
    const float* __restrict__ Wq_b, const float* __restrict__ Wk_w,
    const float* __restrict__ Wk_b, float* __restrict__ Wqk,
    float* __restrict__ bqk)
{
    const int b = blockIdx.x, t = threadIdx.x;
    __shared__ float xr[Cc];
    __shared__ float Q[Cc];
    for (int i = t; i < Cc; i += 256) xr[i] = node[(size_t)b * Nn * Cc + i];
    __syncthreads();
    for (int j = t; j < Cc; j += 256) {
        const float* w = Wq_w + (size_t)j * Cc;
        float s = 0.f;
        for (int k = 0; k < Cc; k++) s = fmaf(xr[k], w[k], s);
        Q[j] = s + Wq_b[j];
    }
    __syncthreads();
    for (int idx = t; idx < E2v * Cc; idx += 256) {
        int e2 = idx >> 9, c = idx & 511;
        float s = 0.f;
        #pragma unroll
        for (int a = 0; a < Aa; a++)
            s = fmaf(Q[a * E2v + e2], Wk_w[(size_t)(a * E2v + e2) * Cc + c], s);
        Wqk[(size_t)b * E2v * Cc + idx] = s;
    }
    if (t < E2v) {
        float s = 0.f;
        #pragma unroll
        for (int a = 0; a < Aa; a++) s = fmaf(Q[a * E2v + t], Wk_b[a * E2v + t], s);
        bqk[b * E2v + t] = s;
    }
}

// ------------------------------------------------- QK -> val (selu(...))
// block: 64 rows (n-tile) x all 64 e2 cols. K=512 chunked by 64.
__global__ __launch_bounds__(256) void k_val(
    const float* __restrict__ node, const float* __restrict__ Wqk,
    const float* __restrict__ bqk, const float* __restrict__ edge,
    const float* __restrict__ emb1, const float* __restrict__ emb2,
    const float* __restrict__ Wew, float* __restrict__ valo)
{
    const int nt = blockIdx.x, b = blockIdx.y, t = threadIdx.x;
    const int n0 = nt * 64;
    __shared__ __align__(16) float as[64][68];
    __shared__ __align__(16) float bs[64][68];
    __shared__ float qs[64][64];
    __shared__ float es[64][Ee];
    __shared__ float wew_s[Ee][Ee + 1];
    const int rg = t >> 4, eg = t & 15;
    const int r0 = rg * 4;
    float acc[4][4] = {};
    for (int k0 = 0; k0 < Cc; k0 += 64) {
        for (int i = t; i < 1024; i += 256) {
            int row = i >> 4, c4 = i & 15;
            *(float4*)&as[row][c4 * 4] =
                *(const float4*)(node + ((size_t)(b * Nn + n0 + row)) * Cc + k0 + c4 * 4);
        }
        for (int i = t; i < 1024; i += 256) {
            int row = i >> 4, c4 = i & 15;
            *(float4*)&bs[row][c4 * 4] =
                *(const float4*)(Wqk + ((size_t)(b * E2v + row)) * Cc + k0 + c4 * 4);
        }
        __syncthreads();
        for (int kk = 0; kk < 64; kk += 4) {
            float4 a4[4], b4[4];
            #pragma unroll
            for (int i = 0; i < 4; i++) a4[i] = *(float4*)&as[r0 + i][kk];
            #pragma unroll
            for (int j = 0; j < 4; j++) b4[j] = *(float4*)&bs[eg + 16 * j][kk];
            #pragma unroll
            for (int i = 0; i < 4; i++)
                #pragma unroll
                for (int j = 0; j < 4; j++) {
                    acc[i][j] = fmaf(a4[i].x, b4[j].x, acc[i][j]);
                    acc[i][j] = fmaf(a4[i].y, b4[j].y, acc[i][j]);
                    acc[i][j] = fmaf(a4[i].z, b4[j].z, acc[i][j]);
                    acc[i][j] = fmaf(a4[i].w, b4[j].w, acc[i][j]);
                }
        }
        __syncthreads();
    }
    #pragma unroll
    for (int i = 0; i < 4; i++)
        #pragma unroll
        for (int j = 0; j < 4; j++)
            qs[r0 + i][eg + 16 * j] = acc[i][j] + bqk[b * E2v + eg + 16 * j];
    for (int i = t; i < 64 * Ee; i += 256) {
        int r = i >> 5, e = i & 31;
        es[r][e] = edge[((size_t)(b * Nn + n0 + r)) * Ee + e];
    }
    for (int i = t; i < Ee * Ee; i += 256) wew_s[i >> 5][i & 31] = Wew[i];
    __syncthreads();
    for (int i = t; i < 2048; i += 256) {
        int r = i >> 5, e = i & 31;
        int n = n0 + r;
        if (n < 1) continue;
        float ew = 0.f;
        #pragma unroll
        for (int j = 0; j < Ee; j++) ew = fmaf(es[r][j], wew_s[e][j], ew);
        size_t g = ((size_t)(b * Nn + n)) * Ee + e;
        float x = rho_f(qs[r][e] * ew) + qs[r][32 + e] * emb1[g] + emb2[g];
        valo[((size_t)(b * NM1 + (n - 1))) * Ee + e] = selu_f(x);
    }
}

// ------------------------------------------------- H1 = gelu(e@Wa1.T), H2 = gelu(e@et1.T + b1)
__global__ __launch_bounds__(256) void k_h12(
    const float* __restrict__ val, const float* __restrict__ Wa1,
    const float* __restrict__ et1, const float* __restrict__ et1b,
    __hip_bfloat16* __restrict__ H1, __hip_bfloat16* __restrict__ H2)
{
    const int ch = blockIdx.x, b = blockIdx.y, t = threadIdx.x;
    const int r0 = ch * 128;
    const int nr = (NM1 - r0) < 128 ? (NM1 - r0) : 128;
    __shared__ float vs[128][33];
    __shared__ float w1[64][33];
    __shared__ float w2[64][33];
    __shared__ float b2s[64];
    for (int i = t; i < 128 * Ee; i += 256) {
        int r = i >> 5, e = i & 31;
        if (r < nr) vs[r][e] = val[((size_t)(b * NM1 + r0 + r)) * Ee + e];
    }
    for (int i = t; i < 64 * Ee; i += 256) {
        int j = i >> 5, k = i & 31;
        w1[j][k] = Wa1[i];
        w2[j][k] = et1[i];
    }
    if (t < 64) b2s[t] = et1b[t];
    __syncthreads();
    for (int i = t; i < 128 * 64; i += 256) {
        int r = i >> 6, j = i & 63;
        if (r >= nr) break;
        float s1 = 0.f, s2 = 0.f;
        #pragma unroll
        for (int k = 0; k < Ee; k++) {
            float v = vs[r][k];
            s1 = fmaf(v, w1[j][k], s1);
            s2 = fmaf(v, w2[j][k], s2);
        }
        size_t o = ((size_t)(b * NM1 + r0 + r)) * Hh + j;
        H1[o] = __float2bfloat16(gelu_f(s1));
        H2[o] = __float2bfloat16(gelu_f(s2 + b2s[j]));
    }
}

// ------------------------------------------------- logits = H1@Wa2.T -> d_out tmp region + (m,l) partials
// block: 64 rows x 128 cols, K=64.
__global__ __launch_bounds__(256) void k_logits(
    const __hip_bfloat16* __restrict__ H1, const float* __restrict__ Wa2,
    float* __restrict__ tmpo, float* __restrict__ pm, float* __restrict__ pl)
{
    const int rt = blockIdx.x, ct = blockIdx.y, b = blockIdx.z, t = threadIdx.x;
    const int r0b = rt * 64, c0b = ct * 128;
    const int nr = (NM1 - r0b) < 64 ? (NM1 - r0b) : 64;
    __shared__ __align__(16) float h1s[64][68];
    __shared__ __align__(16) float w2s[128][68];
    __shared__ float redm[16][128];
    __shared__ float redl[16][128];
    for (int i = t; i < 4096; i += 256) {
        int r = i >> 6, k = i & 63;
        h1s[r][k] = (r < nr) ? __bfloat162float(H1[((size_t)(b * NM1 + r0b + r)) * Hh + k]) : 0.f;
    }
    for (int i = t; i < 128 * 64; i += 256) {
        int c = i >> 6, k = i & 63;
        w2s[c][k] = Wa2[(size_t)(c0b + c) * Hh + k];
    }
    __syncthreads();
    const int rg = t >> 4, cg = t & 15;
    const int r0 = rg * 4;
    float acc[4][8] = {};
    for (int kk = 0; kk < 64; kk += 4) {
        float4 a4[4], b4[8];
        #pragma unroll
        for (int i = 0; i < 4; i++) a4[i] = *(float4*)&h1s[r0 + i][kk];
        #pragma unroll
        for (int j = 0; j < 8; j++) b4[j] = *(float4*)&w2s[cg + 16 * j][kk];
        #pragma unroll
        for (int i = 0; i < 4; i++)
            #pragma unroll
            for (int j = 0; j < 8; j++) {
                acc[i][j] = fmaf(a4[i].x, b4[j].x, acc[i][j]);
                acc[i][j] = fmaf(a4[i].y, b4[j].y, acc[i][j]);
                acc[i][j] = fmaf(a4[i].z, b4[j].z, acc[i][j]);
                acc[i][j] = fmaf(a4[i].w, b4[j].w, acc[i][j]);
            }
    }
    float lm[8], ll[8];
    #pragma unroll
    for (int j = 0; j < 8; j++) { lm[j] = -1e30f; ll[j] = 0.f; }
    #pragma unroll
    for (int i = 0; i < 4; i++) {
        int r = r0 + i;
        if (r < nr) {
            size_t o = ((size_t)(b * NM1 + r0b + r)) * INp + c0b;
            #pragma unroll
            for (int j = 0; j < 8; j++) {
                float x = acc[i][j];
                tmpo[o + cg + 16 * j] = x;   // stash logits in tmp region
                if (x > lm[j]) { ll[j] = ll[j] * expf(lm[j] - x) + 1.f; lm[j] = x; }
                else           { ll[j] += expf(x - lm[j]); }
            }
        }
    }
    #pragma unroll
    for (int j = 0; j < 8; j++) { redm[rg][cg + 16 * j] = lm[j]; redl[rg][cg + 16 * j] = ll[j]; }
    __syncthreads();
    if (t < 128) {
        float m = -1e30f, l = 0.f;
        #pragma unroll
        for (int g = 0; g < 16; g++) {
            float m2 = redm[g][t], l2 = redl[g][t];
            if (m2 > m) { l = l * expf(m - m2) + l2; m = m2; }
            else        { l += l2 * expf(m2 - m); }
        }
        size_t o = ((size_t)(b * 32 + rt)) * INp + c0b + t;
        pm[o] = m; pl[o] = l;
    }
}

// ------------------------------------------------- merge softmax partials -> M, 1/L
__global__ __launch_bounds__(512) void k_merge(
    const float* __restrict__ pm, const float* __restrict__ pl,
    float* __restrict__ Ms, float* __restrict__ iLs)
{
    const int b = blockIdx.x, t = threadIdx.x;   // t = column
    float m = -1e30f, l = 0.f;
    for (int ch = 0; ch < 32; ch++) {
        size_t o = ((size_t)(b * 32 + ch)) * INp + t;
        float m2 = pm[o], l2 = pl[o];
        if (m2 > m) { l = l * expf(m - m2) + l2; m = m2; }
        else        { l += l2 * expf(m2 - m); }
    }
    Ms[b * INp + t] = m;
    iLs[b * INp + t] = 1.0f / l;
}

// ------------------------------------------------- raw GEMM (K=576) + alpha apply + colmax
// raw[c] = dot512(node_row, nt_w[c]) + dot64(h2, et2[c]) + nt_b[c] + et_b2[c]
// tmp    = raw * exp(logit - M)/L ; colmax = max|tmp| per (b,c)
__global__ __launch_bounds__(256) void k_raw(
    const float* __restrict__ node, const __hip_bfloat16* __restrict__ H2,
    const float* __restrict__ ntw, const float* __restrict__ ntb,
    const float* __restrict__ et2, const float* __restrict__ et2b,
    const float* __restrict__ Ms, const float* __restrict__ iLs,
    float* __restrict__ tmpo, unsigned* __restrict__ colmax)
{
    const int rt = blockIdx.x, ct = blockIdx.y, b = blockIdx.z, t = threadIdx.x;
    const int r0b = rt * 64, c0b = ct * 128;
    const int nr = (NM1 - r0b) < 64 ? (NM1 - r0b) : 64;
    __shared__ __align__(16) float ins[64][68];
    __shared__ __align__(16) float ws2[128][68];
    __shared__ float red[16][128];
    const int rg = t >> 4, cg = t & 15;
    const int r0 = rg * 4;
    float acc[4][8] = {};
    for (int k0 = 0; k0 < 576; k0 += 64) {
        if (k0 < Cc) {
            for (int i = t; i < 1024; i += 256) {
                int row = i >> 4, c4 = i & 15;
                float4 v = make_float4(0.f, 0.f, 0.f, 0.f);
                if (row < nr)
                    v = *(const float4*)(node + ((size_t)(b * Nn + r0b + row + 1)) * Cc + k0 + c4 * 4);
                *(float4*)&ins[row][c4 * 4] = v;
            }
            for (int i = t; i < 2048; i += 256) {
                int c = i >> 4, c4 = i & 15;
                *(float4*)&ws2[c][c4 * 4] =
                    *(const float4*)(ntw + (size_t)(c0b + c) * Cc + k0 + c4 * 4);
            }
        } else {
            for (int i = t; i < 4096; i += 256) {
                int row = i >> 6, k = i & 63;
                ins[row][k] = (row < nr)
                    ? __bfloat162float(H2[((size_t)(b * NM1 + r0b + row)) * Hh + k]) : 0.f;
            }
            for (int i = t; i < 8192; i += 256) {
                int c = i >> 6, k = i & 63;
                ws2[c][k] = et2[(size_t)(c0b + c) * Hh + k];
            }
        }
        __syncthreads();
        for (int kk = 0; kk < 64; kk += 4) {
            float4 a4[4], b4[8];
            #pragma unroll
            for (int i = 0; i < 4; i++) a4[i] = *(float4*)&ins[r0 + i][kk];
            #pragma unroll
            for (int j = 0; j < 8; j++) b4[j] = *(float4*)&ws2[cg + 16 * j][kk];
            #pragma unroll
            for (int i = 0; i < 4; i++)
                #pragma unroll
                for (int j = 0; j < 8; j++) {
                    acc[i][j] = fmaf(a4[i].x, b4[j].x, acc[i][j]);
                    acc[i][j] = fmaf(a4[i].y, b4[j].y, acc[i][j]);
                    acc[i][j] = fmaf(a4[i].z, b4[j].z, acc[i][j]);
                    acc[i][j] = fmaf(a4[i].w, b4[j].w, acc[i][j]);
                }
        }
        __syncthreads();
    }
    float Mv[8], iLv[8], bia[8];
    #pragma unroll
    for (int j = 0; j < 8; j++) {
        int c = c0b + cg + 16 * j;
        Mv[j]  = Ms[b * INp + c];
        iLv[j] = iLs[b * INp + c];
        bia[j] = ntb[c] + et2b[c];
    }
    float amax[8] = {};
    #pragma unroll
    for (int i = 0; i < 4; i++) {
        int r = r0 + i;
        if (r < nr) {
            size_t o = ((size_t)(b * NM1 + r0b + r)) * INp + c0b;
            #pragma unroll
            for (int j = 0; j < 8; j++) {
                float logit = tmpo[o + cg + 16 * j];
                float al = expf(logit - Mv[j]) * iLv[j];
                float v = (acc[i][j] + bia[j]) * al;
                tmpo[o + cg + 16 * j] = v;
                amax[j] = fmaxf(amax[j], fabsf(v));
            }
        }
    }
    #pragma unroll
    for (int j = 0; j < 8; j++) red[rg][cg + 16 * j] = amax[j];
    __syncthreads();
    if (t < 128) {
        float m = 0.f;
        #pragma unroll
        for (int g = 0; g < 16; g++) m = fmaxf(m, red[g][t]);
        atomicMax(&colmax[b * INp + c0b + t], __float_as_uint(m));
    }
}

// ------------------------------------------------- mask by thr = colmax/10, column-sum -> out
__global__ __launch_bounds__(256) void k_masksum(
    float* __restrict__ tmpo, const unsigned* __restrict__ colmax,
    float* __restrict__ outp)
{
    const int ch = blockIdx.x, b = blockIdx.y, t = threadIdx.x;
    const int r0 = ch * 128;
    const int nr = (NM1 - r0) < 128 ? (NM1 - r0) : 128;
    const float thr0 = __uint_as_float(colmax[b * INp + t]) / 10.0f;
    const float thr1 = __uint_as_float(colmax[b * INp + 256 + t]) / 10.0f;
    float s0 = 0.f, s1 = 0.f;
    for (int r = 0; r < nr; r++) {
        size_t o = ((size_t)(b * NM1 + r0 + r)) * INp;
        float v0 = tmpo[o + t];
        float v1 = tmpo[o + 256 + t];
        float m0 = (fabsf(v0) >= thr0) ? v0 : 0.f;
        float m1 = (fabsf(v1) >= thr1) ? v1 : 0.f;
        tmpo[o + t] = m0;
        tmpo[o + 256 + t] = m1;
        s0 += m0; s1 += m1;
    }
    atomicAdd(&outp[b * INp + t], s0);
    atomicAdd(&outp[b * INp + 256 + t], s1);
}

extern "C" void kernel_launch(void* const* d_in, const int* in_sizes, int n_in,
                              void* d_out, int out_size, void* d_ws, size_t ws_size,
                              hipStream_t stream)
{
    const float* node = (const float*)d_in[0];
    const float* edge = (const float*)d_in[1];
    const float* emb1 = (const float*)d_in[2];
    const float* emb2 = (const float*)d_in[3];
    const float* Wq_w = (const float*)d_in[4];
    const float* Wq_b = (const float*)d_in[5];
    const float* Wk_w = (const float*)d_in[6];
    const float* Wk_b = (const float*)d_in[7];
    const float* Wew  = (const float*)d_in[8];
    const float* Wa1  = (const float*)d_in[9];
    const float* Wa2  = (const float*)d_in[10];
    const float* ntw  = (const float*)d_in[11];
    const float* ntb  = (const float*)d_in[12];
    const float* et1  = (const float*)d_in[13];
    const float* et1b = (const float*)d_in[14];
    const float* et2  = (const float*)d_in[15];
    const float* et2b = (const float*)d_in[16];

    // ws layout (bytes). pm/pl alias the Wqk region (Wqk dead after k_val).
    char* ws = (char*)d_ws;
    float*          Wqk    = (float*)(ws + 0);                    // 8,388,608
    float*          pm     = (float*)(ws + 0);                    // alias (live later)
    float*          pl     = (float*)(ws + 4194304);
    float*          bqk    = (float*)(ws + 8388608);              // 16,384
    float*          val    = (float*)(ws + 8404992);              // 16,769,024
    __hip_bfloat16* H1     = (__hip_bfloat16*)(ws + 25174016);    // 16,769,024
    __hip_bfloat16* H2     = (__hip_bfloat16*)(ws + 41943040);    // 16,769,024
    float*          Ms     = (float*)(ws + 58712064);             // 131,072
    float*          iLs    = (float*)(ws + 58843136);             // 131,072
    unsigned*       colmax = (unsigned*)(ws + 58974208);          // 131,072  (end ~59.1 MB)

    float* outp = (float*)d_out;            // (B, IN)
    float* tmpo = (float*)d_out + Bb * INp; // (B, NM1, IN); also logits scratch

    k_init   <<<128, 256, 0, stream>>>(outp, colmax);
    k_qwqk   <<<Bb, 256, 0, stream>>>(node, Wq_w, Wq_b, Wk_w, Wk_b, Wqk, bqk);
    k_val    <<<dim3(32, Bb), 256, 0, stream>>>(node, Wqk, bqk, edge, emb1, emb2, Wew, val);
    k_h12    <<<dim3(16, Bb), 256, 0, stream>>>(val, Wa1, et1, et1b, H1, H2);
    k_logits <<<dim3(32, 4, Bb), 256, 0, stream>>>(H1, Wa2, tmpo, pm, pl);
    k_merge  <<<Bb, 512, 0, stream>>>(pm, pl, Ms, iLs);
    k_raw    <<<dim3(32, 4, Bb), 256, 0, stream>>>(node, H2, ntw, ntb, et2, et2b, Ms, iLs, tmpo, colmax);
    k_masksum<<<dim3(16, Bb), 256, 0, stream>>>(tmpo, colmax, outp);
}

// Round 2
// 1870.911 us; speedup vs baseline: 1.3169x; 1.3169x over previous
//
#include <hip/hip_runtime.h>
#include <hip/hip_bf16.h>
#include <math.h>

// Problem constants
#define Bb   64
#define Nn   2048
#define Cc   512
#define Ee   32
#define E2v  64
#define Aa   8
#define INp  512
#define Hh   64
#define NM1  2047   // N-1 rows used after val[:,1:,:]

typedef short  s16x8 __attribute__((ext_vector_type(8)));
typedef float  f32x4 __attribute__((ext_vector_type(4)));
typedef unsigned short ushort_t;

__device__ __forceinline__ float gelu_f(float x){
    return 0.5f * x * (1.0f + erff(x * 0.70710678118654752440f));
}
__device__ __forceinline__ float selu_f(float x){
    const float lam = 1.0507009873554805f, alp = 1.6732632423543772f;
    return x > 0.0f ? lam * x : lam * alp * (expf(x) - 1.0f);
}
__device__ __forceinline__ float rho_f(float x){
    return x > 0.0f ? sqrtf(x) : -sqrtf(-x);
}
__device__ __forceinline__ ushort_t f2bf(float x){
    unsigned u = __float_as_uint(x);
    unsigned r = u + 0x7FFFu + ((u >> 16) & 1u);   // RNE
    return (ushort_t)(r >> 16);
}
__device__ __forceinline__ float bf2f(ushort_t h){
    return __uint_as_float(((unsigned)h) << 16);
}

// ---------------------------------------------------------------- init
__global__ __launch_bounds__(256) void k_init(float* __restrict__ outp,
                                              unsigned* __restrict__ colmax){
    int i = blockIdx.x * 256 + threadIdx.x;
    if (i < Bb * INp) { outp[i] = 0.0f; colmax[i] = 0u; }
}

// ------------------------------------------------- node -> hi/lo bf16 split
__global__ __launch_bounds__(256) void k_conv_node(
    const float* __restrict__ node, ushort_t* __restrict__ hi,
    ushort_t* __restrict__ lo)
{
    const size_t total = (size_t)Bb * Nn * Cc / 4;   // float4 units
    size_t stride = (size_t)gridDim.x * 256;
    for (size_t u = (size_t)blockIdx.x * 256 + threadIdx.x; u < total; u += stride) {
        float4 v = ((const float4*)node)[u];
        ushort4 h, l;
        h.x = f2bf(v.x); l.x = f2bf(v.x - bf2f(h.x));
        h.y = f2bf(v.y); l.y = f2bf(v.y - bf2f(h.y));
        h.z = f2bf(v.z); l.z = f2bf(v.z - bf2f(h.z));
        h.w = f2bf(v.w); l.w = f2bf(v.w - bf2f(h.w));
        ((ushort4*)hi)[u] = h;
        ((ushort4*)lo)[u] = l;
    }
}

// ------------------------------------------------- small weight conversions
__global__ __launch_bounds__(256) void k_conv_w(
    const float* __restrict__ ntw, const float* __restrict__ et2,
    const float* __restrict__ Wa2, ushort_t* __restrict__ ntw_hi,
    ushort_t* __restrict__ ntw_lo, ushort_t* __restrict__ et2_bf,
    ushort_t* __restrict__ Wa2_bf)
{
    int i = blockIdx.x * 256 + threadIdx.x;   // grid covers 262144
    float x = ntw[i];
    ushort_t h = f2bf(x);
    ntw_hi[i] = h;
    ntw_lo[i] = f2bf(x - bf2f(h));
    if (i < INp * Hh) et2_bf[i] = f2bf(et2[i]);
    if (i < INp * Hh) Wa2_bf[i] = f2bf(Wa2[i]);
    else if (i < 2 * INp * Hh) Wa2_bf[0] = Wa2_bf[0]; // no-op keep shape
}

// ------------------------------------------------- Q + folded Wqk/bqk
__global__ __launch_bounds__(256) void k_qwqk(
    const float* __restrict__ node, const float* __restrict__ Wq_w,
    const float* __restrict__ Wq_b, const float* __restrict__ Wk_w,
    const float* __restrict__ Wk_b, float* __restrict__ Wqk,
    float* __restrict__ bqk)
{
    const int b = blockIdx.x, t = threadIdx.x;
    __shared__ float xr[Cc];
    __shared__ float Q[Cc];
    for (int i = t; i < Cc; i += 256) xr[i] = node[(size_t)b * Nn * Cc + i];
    __syncthreads();
    for (int j = t; j < Cc; j += 256) {
        const float* w = Wq_w + (size_t)j * Cc;
        float s = 0.f;
        for (int k = 0; k < Cc; k++) s = fmaf(xr[k], w[k], s);
        Q[j] = s + Wq_b[j];
    }
    __syncthreads();
    for (int idx = t; idx < E2v * Cc; idx += 256) {
        int e2 = idx >> 9, c = idx & 511;
        float s = 0.f;
        #pragma unroll
        for (int a = 0; a < Aa; a++)
            s = fmaf(Q[a * E2v + e2], Wk_w[(size_t)(a * E2v + e2) * Cc + c], s);
        Wqk[(size_t)b * E2v * Cc + idx] = s;
    }
    if (t < E2v) {
        float s = 0.f;
        #pragma unroll
        for (int a = 0; a < Aa; a++) s = fmaf(Q[a * E2v + t], Wk_b[a * E2v + t], s);
        bqk[b * E2v + t] = s;
    }
}

// ------------------------------------------------- QK -> val (selu(...))
__global__ __launch_bounds__(256) void k_val(
    const float* __restrict__ node, const float* __restrict__ Wqk,
    const float* __restrict__ bqk, const float* __restrict__ edge,
    const float* __restrict__ emb1, const float* __restrict__ emb2,
    const float* __restrict__ Wew, float* __restrict__ valo)
{
    const int nt = blockIdx.x, b = blockIdx.y, t = threadIdx.x;
    const int n0 = nt * 64;
    __shared__ __align__(16) float as[64][68];
    __shared__ __align__(16) float bs[64][68];
    __shared__ float qs[64][64];
    __shared__ float es[64][Ee];
    __shared__ float wew_s[Ee][Ee + 1];
    const int rg = t >> 4, eg = t & 15;
    const int r0 = rg * 4;
    float acc[4][4] = {};
    for (int k0 = 0; k0 < Cc; k0 += 64) {
        for (int i = t; i < 1024; i += 256) {
            int row = i >> 4, c4 = i & 15;
            *(float4*)&as[row][c4 * 4] =
                *(const float4*)(node + ((size_t)(b * Nn + n0 + row)) * Cc + k0 + c4 * 4);
        }
        for (int i = t; i < 1024; i += 256) {
            int row = i >> 4, c4 = i & 15;
            *(float4*)&bs[row][c4 * 4] =
                *(const float4*)(Wqk + ((size_t)(b * E2v + row)) * Cc + k0 + c4 * 4);
        }
        __syncthreads();
        for (int kk = 0; kk < 64; kk += 4) {
            float4 a4[4], b4[4];
            #pragma unroll
            for (int i = 0; i < 4; i++) a4[i] = *(float4*)&as[r0 + i][kk];
            #pragma unroll
            for (int j = 0; j < 4; j++) b4[j] = *(float4*)&bs[eg + 16 * j][kk];
            #pragma unroll
            for (int i = 0; i < 4; i++)
                #pragma unroll
                for (int j = 0; j < 4; j++) {
                    acc[i][j] = fmaf(a4[i].x, b4[j].x, acc[i][j]);
                    acc[i][j] = fmaf(a4[i].y, b4[j].y, acc[i][j]);
                    acc[i][j] = fmaf(a4[i].z, b4[j].z, acc[i][j]);
                    acc[i][j] = fmaf(a4[i].w, b4[j].w, acc[i][j]);
                }
        }
        __syncthreads();
    }
    #pragma unroll
    for (int i = 0; i < 4; i++)
        #pragma unroll
        for (int j = 0; j < 4; j++)
            qs[r0 + i][eg + 16 * j] = acc[i][j] + bqk[b * E2v + eg + 16 * j];
    for (int i = t; i < 64 * Ee; i += 256) {
        int r = i >> 5, e = i & 31;
        es[r][e] = edge[((size_t)(b * Nn + n0 + r)) * Ee + e];
    }
    for (int i = t; i < Ee * Ee; i += 256) wew_s[i >> 5][i & 31] = Wew[i];
    __syncthreads();
    for (int i = t; i < 2048; i += 256) {
        int r = i >> 5, e = i & 31;
        int n = n0 + r;
        if (n < 1) continue;
        float ew = 0.f;
        #pragma unroll
        for (int j = 0; j < Ee; j++) ew = fmaf(es[r][j], wew_s[e][j], ew);
        size_t g = ((size_t)(b * Nn + n)) * Ee + e;
        float x = rho_f(qs[r][e] * ew) + qs[r][32 + e] * emb1[g] + emb2[g];
        valo[((size_t)(b * NM1 + (n - 1))) * Ee + e] = selu_f(x);
    }
}

// ------------------------------------------------- H1, H2 (bf16)
__global__ __launch_bounds__(256) void k_h12(
    const float* __restrict__ val, const float* __restrict__ Wa1,
    const float* __restrict__ et1, const float* __restrict__ et1b,
    ushort_t* __restrict__ H1, ushort_t* __restrict__ H2)
{
    const int ch = blockIdx.x, b = blockIdx.y, t = threadIdx.x;
    const int r0 = ch * 128;
    const int nr = (NM1 - r0) < 128 ? (NM1 - r0) : 128;
    __shared__ float vs[128][33];
    __shared__ float w1[64][33];
    __shared__ float w2[64][33];
    __shared__ float b2s[64];
    for (int i = t; i < 128 * Ee; i += 256) {
        int r = i >> 5, e = i & 31;
        if (r < nr) vs[r][e] = val[((size_t)(b * NM1 + r0 + r)) * Ee + e];
    }
    for (int i = t; i < 64 * Ee; i += 256) {
        int j = i >> 5, k = i & 31;
        w1[j][k] = Wa1[i];
        w2[j][k] = et1[i];
    }
    if (t < 64) b2s[t] = et1b[t];
    __syncthreads();
    for (int i = t; i < 128 * 64; i += 256) {
        int r = i >> 6, j = i & 63;
        if (r >= nr) break;
        float s1 = 0.f, s2 = 0.f;
        #pragma unroll
        for (int k = 0; k < Ee; k++) {
            float v = vs[r][k];
            s1 = fmaf(v, w1[j][k], s1);
            s2 = fmaf(v, w2[j][k], s2);
        }
        size_t o = ((size_t)(b * NM1 + r0 + r)) * Hh + j;
        H1[o] = f2bf(gelu_f(s1));
        H2[o] = f2bf(gelu_f(s2 + b2s[j]));
    }
}

// ------------------------------------------------- softmax partials (m,l) only
__global__ __launch_bounds__(256) void k_logits(
    const ushort_t* __restrict__ H1, const float* __restrict__ Wa2,
    float* __restrict__ pm, float* __restrict__ pl)
{
    const int rt = blockIdx.x, ct = blockIdx.y, b = blockIdx.z, t = threadIdx.x;
    const int r0b = rt * 64, c0b = ct * 128;
    const int nr = (NM1 - r0b) < 64 ? (NM1 - r0b) : 64;
    __shared__ __align__(16) float h1s[64][68];
    __shared__ __align__(16) float w2s[128][68];
    __shared__ float redm[16][128];
    __shared__ float redl[16][128];
    for (int i = t; i < 4096; i += 256) {
        int r = i >> 6, k = i & 63;
        h1s[r][k] = (r < nr) ? bf2f(H1[((size_t)(b * NM1 + r0b + r)) * Hh + k]) : 0.f;
    }
    for (int i = t; i < 128 * 64; i += 256) {
        int c = i >> 6, k = i & 63;
        w2s[c][k] = Wa2[(size_t)(c0b + c) * Hh + k];
    }
    __syncthreads();
    const int rg = t >> 4, cg = t & 15;
    const int r0 = rg * 4;
    float acc[4][8] = {};
    for (int kk = 0; kk < 64; kk += 4) {
        float4 a4[4], b4[8];
        #pragma unroll
        for (int i = 0; i < 4; i++) a4[i] = *(float4*)&h1s[r0 + i][kk];
        #pragma unroll
        for (int j = 0; j < 8; j++) b4[j] = *(float4*)&w2s[cg + 16 * j][kk];
        #pragma unroll
        for (int i = 0; i < 4; i++)
            #pragma unroll
            for (int j = 0; j < 8; j++) {
                acc[i][j] = fmaf(a4[i].x, b4[j].x, acc[i][j]);
                acc[i][j] = fmaf(a4[i].y, b4[j].y, acc[i][j]);
                acc[i][j] = fmaf(a4[i].z, b4[j].z, acc[i][j]);
                acc[i][j] = fmaf(a4[i].w, b4[j].w, acc[i][j]);
            }
    }
    float lm[8], ll[8];
    #pragma unroll
    for (int j = 0; j < 8; j++) { lm[j] = -1e30f; ll[j] = 0.f; }
    #pragma unroll
    for (int i = 0; i < 4; i++) {
        int r = r0 + i;
        if (r < nr) {
            #pragma unroll
            for (int j = 0; j < 8; j++) {
                float x = acc[i][j];
                if (x > lm[j]) { ll[j] = ll[j] * expf(lm[j] - x) + 1.f; lm[j] = x; }
                else           { ll[j] += expf(x - lm[j]); }
            }
        }
    }
    #pragma unroll
    for (int j = 0; j < 8; j++) { redm[rg][cg + 16 * j] = lm[j]; redl[rg][cg + 16 * j] = ll[j]; }
    __syncthreads();
    if (t < 128) {
        float m = -1e30f, l = 0.f;
        #pragma unroll
        for (int g = 0; g < 16; g++) {
            float m2 = redm[g][t], l2 = redl[g][t];
            if (m2 > m) { l = l * expf(m - m2) + l2; m = m2; }
            else        { l += l2 * expf(m2 - m); }
        }
        size_t o = ((size_t)(b * 32 + rt)) * INp + c0b + t;
        pm[o] = m; pl[o] = l;
    }
}

// ------------------------------------------------- merge softmax partials -> M, 1/L
__global__ __launch_bounds__(512) void k_merge(
    const float* __restrict__ pm, const float* __restrict__ pl,
    float* __restrict__ Ms, float* __restrict__ iLs)
{
    const int b = blockIdx.x, t = threadIdx.x;
    float m = -1e30f, l = 0.f;
    for (int ch = 0; ch < 32; ch++) {
        size_t o = ((size_t)(b * 32 + ch)) * INp + t;
        float m2 = pm[o], l2 = pl[o];
        if (m2 > m) { l = l * expf(m - m2) + l2; m = m2; }
        else        { l += l2 * expf(m2 - m); }
    }
    Ms[b * INp + t] = m;
    iLs[b * INp + t] = 1.0f / l;
}

// ------------------------------------------------- MFMA raw GEMM + logit recompute + alpha + colmax
// 128x128 tile per block; 4 waves in 2x2; split-bf16 (hi/lo) for K=512 node part.
struct SMemStage {
    ushort_t Ah[128 * 72];
    ushort_t Al[128 * 72];
    ushort_t Bh[128 * 72];
    ushort_t Bl[128 * 72];
};
union SMemU {
    SMemStage s;
    float ep[128 * 132];
};

__global__ __launch_bounds__(256) void k_raw(
    const ushort_t* __restrict__ node_hi, const ushort_t* __restrict__ node_lo,
    const ushort_t* __restrict__ H1, const ushort_t* __restrict__ H2,
    const ushort_t* __restrict__ ntw_hi, const ushort_t* __restrict__ ntw_lo,
    const ushort_t* __restrict__ et2_bf, const ushort_t* __restrict__ Wa2_bf,
    const float* __restrict__ ntb, const float* __restrict__ et2b,
    const float* __restrict__ Ms, const float* __restrict__ iLs,
    float* __restrict__ tmpo, unsigned* __restrict__ colmax)
{
    const int ct = blockIdx.x, rt = blockIdx.y, b = blockIdx.z;
    const int t = threadIdx.x;
    const int c0b = ct * 128, r0b = rt * 128;
    __shared__ __align__(16) SMemU sm;
    __shared__ float Mv_s[128], iL_s[128], bias_s[128];
    __shared__ float colred[4][64];

    const int w = t >> 6, l = t & 63;
    const int wr = w >> 1, wc = w & 1;
    const int lm = l & 15, lq = l >> 4;

    if (t < 128) {
        Mv_s[t]   = Ms[b * INp + c0b + t];
        iL_s[t]   = iLs[b * INp + c0b + t];
        bias_s[t] = ntb[c0b + t] + et2b[c0b + t];
    }

    // ---- phase 0: stage H1/Wa2 (logit) and H2/et2 (edge_t) tiles, K=64
    for (int i = t; i < 1024; i += 256) {
        int r = i >> 3, kg = i & 7;
        float4 z = make_float4(0.f, 0.f, 0.f, 0.f);
        float4 v1 = z, v2 = z;
        if (r0b + r < NM1) {
            v1 = *(const float4*)(H1 + ((size_t)(b * NM1 + r0b + r)) * Hh + kg * 8);
            v2 = *(const float4*)(H2 + ((size_t)(b * NM1 + r0b + r)) * Hh + kg * 8);
        }
        *(float4*)&sm.s.Ah[r * 72 + kg * 8] = v1;
        *(float4*)&sm.s.Al[r * 72 + kg * 8] = v2;
        *(float4*)&sm.s.Bh[r * 72 + kg * 8] =
            *(const float4*)(Wa2_bf + (size_t)(c0b + r) * Hh + kg * 8);
        *(float4*)&sm.s.Bl[r * 72 + kg * 8] =
            *(const float4*)(et2_bf + (size_t)(c0b + r) * Hh + kg * 8);
    }
    __syncthreads();

    // ---- phase 1: logits = H1 @ Wa2^T  (bf16 MFMA, K=64) -> alpha
    f32x4 lac[4][4];
    #pragma unroll
    for (int m = 0; m < 4; m++)
        #pragma unroll
        for (int n = 0; n < 4; n++) lac[m][n] = (f32x4){0.f, 0.f, 0.f, 0.f};
    #pragma unroll
    for (int kk = 0; kk < 64; kk += 32) {
        s16x8 af[4], bf_[4];
        #pragma unroll
        for (int m = 0; m < 4; m++)
            af[m] = *(const s16x8*)&sm.s.Ah[(wr * 64 + m * 16 + lm) * 72 + kk + lq * 8];
        #pragma unroll
        for (int n = 0; n < 4; n++)
            bf_[n] = *(const s16x8*)&sm.s.Bh[(wc * 64 + n * 16 + lm) * 72 + kk + lq * 8];
        #pragma unroll
        for (int m = 0; m < 4; m++)
            #pragma unroll
            for (int n = 0; n < 4; n++)
                lac[m][n] = __builtin_amdgcn_mfma_f32_16x16x32_bf16(af[m], bf_[n], lac[m][n], 0, 0, 0);
    }
    float alpha[4][4][4];
    #pragma unroll
    for (int n = 0; n < 4; n++) {
        float Mn  = Mv_s[wc * 64 + n * 16 + lm];
        float iLn = iL_s[wc * 64 + n * 16 + lm];
        #pragma unroll
        for (int m = 0; m < 4; m++)
            #pragma unroll
            for (int j = 0; j < 4; j++) {
                int row = r0b + wr * 64 + m * 16 + lq * 4 + j;
                alpha[m][n][j] = (row < NM1) ? __expf(lac[m][n][j] - Mn) * iLn : 0.f;
            }
    }

    // ---- phase 2: racc = H2 @ et2^T (K=64)
    f32x4 racc[4][4];
    #pragma unroll
    for (int m = 0; m < 4; m++)
        #pragma unroll
        for (int n = 0; n < 4; n++) racc[m][n] = (f32x4){0.f, 0.f, 0.f, 0.f};
    #pragma unroll
    for (int kk = 0; kk < 64; kk += 32) {
        s16x8 af[4], bf_[4];
        #pragma unroll
        for (int m = 0; m < 4; m++)
            af[m] = *(const s16x8*)&sm.s.Al[(wr * 64 + m * 16 + lm) * 72 + kk + lq * 8];
        #pragma unroll
        for (int n = 0; n < 4; n++)
            bf_[n] = *(const s16x8*)&sm.s.Bl[(wc * 64 + n * 16 + lm) * 72 + kk + lq * 8];
        #pragma unroll
        for (int m = 0; m < 4; m++)
            #pragma unroll
            for (int n = 0; n < 4; n++)
                racc[m][n] = __builtin_amdgcn_mfma_f32_16x16x32_bf16(af[m], bf_[n], racc[m][n], 0, 0, 0);
    }

    // ---- phase 3: racc += node @ ntw^T via split-bf16, K=512 in 8 chunks of 64
    for (int k0 = 0; k0 < Cc; k0 += 64) {
        __syncthreads();
        for (int i = t; i < 1024; i += 256) {
            int r = i >> 3, kg = i & 7;
            float4 va = make_float4(0.f, 0.f, 0.f, 0.f), vb = va;
            if (r0b + 1 + r < Nn) {
                size_t g = ((size_t)(b * Nn + r0b + 1 + r)) * Cc + k0 + kg * 8;
                va = *(const float4*)(node_hi + g);
                vb = *(const float4*)(node_lo + g);
            }
            *(float4*)&sm.s.Ah[r * 72 + kg * 8] = va;
            *(float4*)&sm.s.Al[r * 72 + kg * 8] = vb;
            size_t gw = (size_t)(c0b + r) * Cc + k0 + kg * 8;
            *(float4*)&sm.s.Bh[r * 72 + kg * 8] = *(const float4*)(ntw_hi + gw);
            *(float4*)&sm.s.Bl[r * 72 + kg * 8] = *(const float4*)(ntw_lo + gw);
        }
        __syncthreads();
        #pragma unroll
        for (int kk = 0; kk < 64; kk += 32) {
            s16x8 ah[4], al_[4], bh[4], bl[4];
            #pragma unroll
            for (int m = 0; m < 4; m++) {
                int off = (wr * 64 + m * 16 + lm) * 72 + kk + lq * 8;
                ah[m]  = *(const s16x8*)&sm.s.Ah[off];
                al_[m] = *(const s16x8*)&sm.s.Al[off];
            }
            #pragma unroll
            for (int n = 0; n < 4; n++) {
                int off = (wc * 64 + n * 16 + lm) * 72 + kk + lq * 8;
                bh[n] = *(const s16x8*)&sm.s.Bh[off];
                bl[n] = *(const s16x8*)&sm.s.Bl[off];
            }
            #pragma unroll
            for (int m = 0; m < 4; m++)
                #pragma unroll
                for (int n = 0; n < 4; n++) {
                    racc[m][n] = __builtin_amdgcn_mfma_f32_16x16x32_bf16(ah[m],  bh[n], racc[m][n], 0, 0, 0);
                    racc[m][n] = __builtin_amdgcn_mfma_f32_16x16x32_bf16(ah[m],  bl[n], racc[m][n], 0, 0, 0);
                    racc[m][n] = __builtin_amdgcn_mfma_f32_16x16x32_bf16(al_[m], bh[n], racc[m][n], 0, 0, 0);
                }
        }
    }
    __syncthreads();   // staging LDS reads done; safe to reuse as ep

    // ---- epilogue: v = (raw + bias) * alpha; transpose via LDS; colmax
    float cmax[4] = {0.f, 0.f, 0.f, 0.f};
    #pragma unroll
    for (int m = 0; m < 4; m++)
        #pragma unroll
        for (int n = 0; n < 4; n++) {
            float bia = bias_s[wc * 64 + n * 16 + lm];
            #pragma unroll
            for (int j = 0; j < 4; j++) {
                float v = (racc[m][n][j] + bia) * alpha[m][n][j];
                sm.ep[(wr * 64 + m * 16 + lq * 4 + j) * 132 + wc * 64 + n * 16 + lm] = v;
                cmax[n] = fmaxf(cmax[n], fabsf(v));
            }
        }
    #pragma unroll
    for (int n = 0; n < 4; n++) {
        cmax[n] = fmaxf(cmax[n], __shfl_xor(cmax[n], 16, 64));
        cmax[n] = fmaxf(cmax[n], __shfl_xor(cmax[n], 32, 64));
    }
    if (lq == 0) {
        #pragma unroll
        for (int n = 0; n < 4; n++) colred[w][n * 16 + lm] = cmax[n];
    }
    __syncthreads();
    if (t < 128) {
        int half = t >> 6;
        float m = fmaxf(colred[half][t & 63], colred[2 + half][t & 63]);
        atomicMax(&colmax[b * INp + c0b + t], __float_as_uint(m));
    }
    for (int i = t; i < 4096; i += 256) {
        int r = i >> 5, cg = i & 31;
        if (r0b + r < NM1)
            *(float4*)(tmpo + ((size_t)(b * NM1 + r0b + r)) * INp + c0b + cg * 4) =
                *(float4*)&sm.ep[r * 132 + cg * 4];
    }
}

// ------------------------------------------------- mask by thr = colmax/10, column-sum -> out
__global__ __launch_bounds__(256) void k_masksum(
    float* __restrict__ tmpo, const unsigned* __restrict__ colmax,
    float* __restrict__ outp)
{
    const int ch = blockIdx.x, b = blockIdx.y, t = threadIdx.x;
    const int r0 = ch * 128;
    const int nr = (NM1 - r0) < 128 ? (NM1 - r0) : 128;
    const float thr0 = __uint_as_float(colmax[b * INp + t]) / 10.0f;
    const float thr1 = __uint_as_float(colmax[b * INp + 256 + t]) / 10.0f;
    float s0 = 0.f, s1 = 0.f;
    for (int r = 0; r < nr; r++) {
        size_t o = ((size_t)(b * NM1 + r0 + r)) * INp;
        float v0 = tmpo[o + t];
        float v1 = tmpo[o + 256 + t];
        float m0 = (fabsf(v0) >= thr0) ? v0 : 0.f;
        float m1 = (fabsf(v1) >= thr1) ? v1 : 0.f;
        tmpo[o + t] = m0;
        tmpo[o + 256 + t] = m1;
        s0 += m0; s1 += m1;
    }
    atomicAdd(&outp[b * INp + t], s0);
    atomicAdd(&outp[b * INp + 256 + t], s1);
}

extern "C" void kernel_launch(void* const* d_in, const int* in_sizes, int n_in,
                              void* d_out, int out_size, void* d_ws, size_t ws_size,
                              hipStream_t stream)
{
    const float* node = (const float*)d_in[0];
    const float* edge = (const float*)d_in[1];
    const float* emb1 = (const float*)d_in[2];
    const float* emb2 = (const float*)d_in[3];
    const float* Wq_w = (const float*)d_in[4];
    const float* Wq_b = (const float*)d_in[5];
    const float* Wk_w = (const float*)d_in[6];
    const float* Wk_b = (const float*)d_in[7];
    const float* Wew  = (const float*)d_in[8];
    const float* Wa1  = (const float*)d_in[9];
    const float* Wa2  = (const float*)d_in[10];
    const float* ntw  = (const float*)d_in[11];
    const float* ntb  = (const float*)d_in[12];
    const float* et1  = (const float*)d_in[13];
    const float* et1b = (const float*)d_in[14];
    const float* et2  = (const float*)d_in[15];
    const float* et2b = (const float*)d_in[16];

    // ws layout (bytes). pm/pl alias Wqk region (Wqk dead after k_val).
    char* ws = (char*)d_ws;
    float*    Wqk     = (float*)(ws + 0);                       // 8,388,608
    float*    pm      = (float*)(ws + 0);                       // alias
    float*    pl      = (float*)(ws + 4194304);
    float*    bqk     = (float*)(ws + 8388608);                 // 16 KB
    float*    val     = (float*)(ws + 8404992);                 // 16,769,024
    ushort_t* H1      = (ushort_t*)(ws + 25174016);             // 8,384,512 used (bf16)
    ushort_t* H2      = (ushort_t*)(ws + 41943040);
    float*    Ms      = (float*)(ws + 58712064);
    float*    iLs     = (float*)(ws + 58843136);
    unsigned* colmax  = (unsigned*)(ws + 58974208);
    ushort_t* node_hi = (ushort_t*)(ws + 59105280);             // 134,217,728
    ushort_t* node_lo = (ushort_t*)(ws + 193323008);            // 134,217,728
    ushort_t* ntw_hi  = (ushort_t*)(ws + 327540736);            // 524,288
    ushort_t* ntw_lo  = (ushort_t*)(ws + 328065024);            // 524,288
    ushort_t* et2_bf  = (ushort_t*)(ws + 328589312);            // 65,536
    ushort_t* Wa2_bf  = (ushort_t*)(ws + 328654848);            // 65,536

    float* outp = (float*)d_out;            // (B, IN)
    float* tmpo = (float*)d_out + Bb * INp; // (B, NM1, IN)

    k_init     <<<128, 256, 0, stream>>>(outp, colmax);
    k_conv_node<<<8192, 256, 0, stream>>>(node, node_hi, node_lo);
    k_conv_w   <<<1024, 256, 0, stream>>>(ntw, et2, Wa2, ntw_hi, ntw_lo, et2_bf, Wa2_bf);
    k_qwqk     <<<Bb, 256, 0, stream>>>(node, Wq_w, Wq_b, Wk_w, Wk_b, Wqk, bqk);
    k_val      <<<dim3(32, Bb), 256, 0, stream>>>(node, Wqk, bqk, edge, emb1, emb2, Wew, val);
    k_h12      <<<dim3(16, Bb), 256, 0, stream>>>(val, Wa1, et1, et1b, H1, H2);
    k_logits   <<<dim3(32, 4, Bb), 256, 0, stream>>>(H1, Wa2, pm, pl);
    k_merge    <<<Bb, 512, 0, stream>>>(pm, pl, Ms, iLs);
    k_raw      <<<dim3(4, 16, Bb), 256, 0, stream>>>(node_hi, node_lo, H1, H2,
                 ntw_hi, ntw_lo, et2_bf, Wa2_bf, ntb, et2b, Ms, iLs, tmpo, colmax);
    k_masksum  <<<dim3(16, Bb), 256, 0, stream>>>(tmpo, colmax, outp);
}